// Round 1
// baseline (251.076 us; speedup 1.0000x reference)
//
#include <hip/hip_runtime.h>
#include <math.h>

// Problem constants (fixed by the reference)
constexpr int kVocab  = 50000;
constexpr int kEmb    = 128;
constexpr int kRegion = 7;
constexpr int kRadius = 3;
constexpr int kBatch  = 32;
constexpr int kSeq    = 1024;
constexpr int kPos    = kBatch * kSeq;   // 32768 output rows
constexpr int kPosPerBlock = 8;          // 256 threads / (32 lanes per position)

// h[b,s,e] = max_r U_full[win*7+r][e] * W_full[t][e]
//   W_full[t]     = (t > 0) ? W[t-1]          : 0
//   U_full[t*7+r] = (t > 0) ? U[(t-1)*7 + r]  : 0   (covers padding AND token 0)
__global__ __launch_bounds__(256) void region_encoder_kernel(
    const int*   __restrict__ seq,   // (32, 1024)
    const float* __restrict__ W,     // (49999, 128)
    const float* __restrict__ U,     // (349993, 128)
    float*       __restrict__ out)   // (32, 1024, 128)
{
    const int lane     = threadIdx.x & 31;   // element quad: covers e = lane*4 .. lane*4+3
    const int posLocal = threadIdx.x >> 5;
    const int pos      = blockIdx.x * kPosPerBlock + posLocal;
    const int b        = pos >> 10;          // kSeq == 1024
    const int s        = pos & (kSeq - 1);

    // ---- center token -> W row (coalesced 512B per position) ----
    const int t = seq[pos];
    float4 wv = make_float4(0.f, 0.f, 0.f, 0.f);
    if (t > 0) {
        wv = ((const float4*)(W + (size_t)(t - 1) * kEmb))[lane];
    }

    // ---- gather the 7 window token ids (broadcast reads, L1-served) ----
    int wt[kRegion];
#pragma unroll
    for (int r = 0; r < kRegion; ++r) {
        const int sp = s + r - kRadius;
        wt[r] = (sp >= 0 && sp < kSeq) ? seq[b * kSeq + sp] : 0;
    }

    // ---- issue all 7 U-row loads up front (keep 7 dwordx4 in flight) ----
    float4 uv[kRegion];
#pragma unroll
    for (int r = 0; r < kRegion; ++r) {
        if (wt[r] > 0) {
            const size_t row = (size_t)(wt[r] - 1) * kRegion + r;
            uv[r] = ((const float4*)(U + row * kEmb))[lane];
        } else {
            uv[r] = make_float4(0.f, 0.f, 0.f, 0.f);
        }
    }

    // ---- max over region of elementwise products ----
    float4 m;
    m.x = uv[0].x * wv.x;
    m.y = uv[0].y * wv.y;
    m.z = uv[0].z * wv.z;
    m.w = uv[0].w * wv.w;
#pragma unroll
    for (int r = 1; r < kRegion; ++r) {
        m.x = fmaxf(m.x, uv[r].x * wv.x);
        m.y = fmaxf(m.y, uv[r].y * wv.y);
        m.z = fmaxf(m.z, uv[r].z * wv.z);
        m.w = fmaxf(m.w, uv[r].w * wv.w);
    }

    ((float4*)out)[(size_t)pos * (kEmb / 4) + lane] = m;
}

extern "C" void kernel_launch(void* const* d_in, const int* in_sizes, int n_in,
                              void* d_out, int out_size, void* d_ws, size_t ws_size,
                              hipStream_t stream) {
    const int*   seq = (const int*)d_in[0];
    const float* W   = (const float*)d_in[1];
    const float* U   = (const float*)d_in[2];
    float*       out = (float*)d_out;

    const int blocks = kPos / kPosPerBlock;  // 4096
    region_encoder_kernel<<<dim3(blocks), dim3(256), 0, stream>>>(seq, W, U, out);
}